// Round 13
// baseline (104.805 us; speedup 1.0000x reference)
//
#include <hip/hip_runtime.h>
#include <hip/hip_bf16.h>

#define NB 8192
#define DD 256
#define INV_T (1.0f/0.07f)
#define LOG2E 1.4426950408889634f
#define K1    (INV_T*LOG2E)          // logit (log2 units) = acc*K1 - K1
#define CEXP  6.2087204553847255e-7f // exp(-1/0.07): folds the -K1 term into se
#define NSTRIP 32
#define TILE 256
#define BN 64
#define BUFB (BN*DD*2)       // 32768 bytes per LDS buffer

typedef __attribute__((ext_vector_type(8))) short s8v;   // 8 bf16
typedef __attribute__((ext_vector_type(4))) float f4v;   // 4 f32 acc
typedef unsigned int u32;
typedef unsigned short u16;

// workspace layout (bytes)
#define OFF_FB   0                                  // bf16 normalized features: 4 MB
#define OFF_SEA  (4*1024*1024)                      // f32[8192] row exp-sum atomics
#define OFF_CE   (OFF_SEA + NB*4)                   // f32[32][8192] col-sum slots
#define OFF_C    (OFF_CE + NSTRIP*NB*4)             // f32[128][256] class centroids
#define OFF_CL   (OFF_C + 128*DD*4)                 // f32[32]
#define OFF_CV   (OFF_CL + 256)                     // f32[32]
#define OFF_CNT  (OFF_CV + 256)                     // int[1]

__device__ __forceinline__ float bf2f(short h) {
    u32 x = ((u32)(u16)h) << 16;
    return *(float*)&x;
}

// wave-per-row normalize; blocks 0..31 zero SEa, 64..191 zero C; block 0 zeros cnt
__global__ void k_norm(const float* __restrict__ feat,
                       __hip_bfloat16* __restrict__ fb,
                       float* __restrict__ SEa, float* __restrict__ C,
                       int* __restrict__ cnt) {
    const int t = threadIdx.x;
    if (blockIdx.x == 0 && t == 0) *cnt = 0;
    if (blockIdx.x < 32) SEa[blockIdx.x * 256 + t] = 0.f;
    else if (blockIdx.x >= 64 && blockIdx.x < 192) C[(blockIdx.x - 64) * 256 + t] = 0.f;
    const int w = t >> 6, l = t & 63;
    const int row = blockIdx.x * 4 + w;
    const float4 v = ((const float4*)feat)[row * 64 + l];
    float s = v.x * v.x + v.y * v.y + v.z * v.z + v.w * v.w;
    #pragma unroll
    for (int d = 32; d; d >>= 1) s += __shfl_xor(s, d, 64);
    const float scale = 1.0f / fmaxf(sqrtf(s), 1e-12f);
    __hip_bfloat16 h0 = __float2bfloat16(v.x * scale);
    __hip_bfloat16 h1 = __float2bfloat16(v.y * scale);
    __hip_bfloat16 h2 = __float2bfloat16(v.z * scale);
    __hip_bfloat16 h3 = __float2bfloat16(v.w * scale);
    ushort4 o;
    o.x = *(u16*)&h0; o.y = *(u16*)&h1; o.z = *(u16*)&h2; o.w = *(u16*)&h3;
    ((ushort4*)fb)[row * 64 + l] = o;
}

__device__ __forceinline__ void gld16(const void* g, void* l) {
    __builtin_amdgcn_global_load_lds((const __attribute__((address_space(1))) u32*)g,
                                     (__attribute__((address_space(3))) u32*)l, 16, 0, 0);
}

// Symmetric fused sim + exp row/col reduction — persistent balanced blocks.
// Positive-pair sums handled ANALYTICALLY via class centroids (k_rows), so the
// epilogue is exp-only. Pair p = (strip 31-s, strip s): 132 64-col iters, 16 blocks
// per pair. Row exp-sums -> atomicAdd SEa; col exp-sums -> single-writer CE slots.
// One barrier per iter (parity-buffered col staging). After the main loop each
// block accumulates its slice of the class-centroid matrix C.
__launch_bounds__(512)
__global__ void k_main(const __hip_bfloat16* __restrict__ fb,
                       const int* __restrict__ lab,
                       float* __restrict__ SEa, float* __restrict__ CE,
                       float* __restrict__ C) {
    __shared__ __align__(16) char ldsB[2 * BUFB];   // 64 KB, XOR-swizzled
    __shared__ float ldsCol[2][8][BN];              // 4 KB parity-buffered col partials
    const int tid = threadIdx.x;
    const int w = tid >> 6;
    const int l = tid & 63;
    const int l15 = l & 15, lg = l >> 4;

    const int s = blockIdx.x >> 4;          // pair 0..15
    const int j = blockIdx.x & 15;          // block within pair
    const int nA = 4 * (32 - s);            // iters of strip A = 31-s
    const int cnt = 8 + (j >= 12 ? 1 : 0);  // 12x8 + 4x9 = 132
    const int off = 8 * j + (j > 12 ? j - 12 : 0);

    s8v a[2][8];
    int wbase = 0;
    auto loadA = [&](int r) {
        wbase = r * TILE + w * 32;
        #pragma unroll
        for (int m = 0; m < 2; m++)
            #pragma unroll
            for (int kk = 0; kk < 8; kk++)
                a[m][kk] = *(const s8v*)(fb + (wbase + m * 16 + l15) * DD + kk * 32 + lg * 8);
    };

    float sE[8];
    #pragma unroll
    for (int i = 0; i < 8; i++) sE[i] = 0.f;
    auto flushRows = [&]() {
        #pragma unroll
        for (int idx = 0; idx < 8; idx++)
            #pragma unroll
            for (int d = 1; d < 16; d <<= 1)
                sE[idx] += __shfl_xor(sE[idx], d, 16);
        if (l15 == 0) {
            #pragma unroll
            for (int idx = 0; idx < 8; idx++) {
                const int row = wbase + (idx >> 2) * 16 + lg * 4 + (idx & 3);
                atomicAdd(&SEa[row], sE[idx]);
            }
        }
        #pragma unroll
        for (int i = 0; i < 8; i++) sE[i] = 0.f;
    };

    // stage 64x256 bf16 tile: linear LDS dest, inverse-swizzled global source
    auto stage = [&](int g, int bufoff) {
        const int c0 = (g < nA ? g : g - nA) * 64;
        const char* gt = (const char*)fb + (size_t)c0 * (DD * 2);
        #pragma unroll
        for (int i = 0; i < 4; i++) {
            const int x = i * 8192 + (tid << 4);
            const int br = x >> 9;
            const int inrow = x & 511;
            gld16(gt + br * 512 + (inrow ^ ((br & 7) << 4)),
                  ldsB + bufoff + i * 8192 + w * 1024);
        }
    };

    stage(off, 0);
    loadA(off < nA ? 31 - s : s);
    __syncthreads();

    for (int t = 0; t < cnt; t++) {
        const int g = off + t;
        const int curoff = (t & 1) * BUFB;
        if (t + 1 < cnt) stage(g + 1, curoff ^ BUFB);

        const int r = (g < nA) ? 31 - s : s;
        const int i = (g < nA) ? g : g - nA;
        const int col0 = i * 64;
        const bool diag = ((i >> 2) == r);

        f4v acc[2][4];
        #pragma unroll
        for (int m = 0; m < 2; m++)
            #pragma unroll
            for (int n = 0; n < 4; n++)
                acc[m][n] = (f4v){0.f, 0.f, 0.f, 0.f};

        #pragma unroll
        for (int kk = 0; kk < 8; kk++) {
            s8v bfr[4];
            #pragma unroll
            for (int n = 0; n < 4; n++) {
                const int br = n * 16 + l15;
                const int ad = (br * 512 + kk * 64 + lg * 16) ^ ((br & 7) << 4);
                bfr[n] = *(const s8v*)(ldsB + curoff + ad);
            }
            #pragma unroll
            for (int m = 0; m < 2; m++)
                #pragma unroll
                for (int n = 0; n < 4; n++)
                    acc[m][n] = __builtin_amdgcn_mfma_f32_16x16x32_bf16(a[m][kk], bfr[n], acc[m][n], 0, 0, 0);
        }

        float cE[4];
        #pragma unroll
        for (int n = 0; n < 4; n++) {
            float cEn = 0.f;
            #pragma unroll
            for (int m = 0; m < 2; m++)
                #pragma unroll
                for (int rr = 0; rr < 4; rr++) {
                    const int idx = m * 4 + rr;
                    float e = exp2f(acc[m][n][rr] * K1);  // true e = CEXP * this
                    if (diag) {
                        const int row = wbase + m * 16 + lg * 4 + rr;
                        const int coln = col0 + n * 16 + l15;
                        e = (row != coln) ? e : 0.f;
                    }
                    sE[idx] += e;
                    cEn += e;
                }
            cE[n] = cEn;
        }

        if (!diag) {
            #pragma unroll
            for (int n = 0; n < 4; n++) {
                cE[n] += __shfl_xor(cE[n], 16, 64);
                cE[n] += __shfl_xor(cE[n], 32, 64);
            }
            if (l < 16) {
                #pragma unroll
                for (int n = 0; n < 4; n++)
                    ldsCol[t & 1][w][n * 16 + l15] = cE[n];
            }
        }
        __syncthreads();   // buf(t+1) staged; cur-buf reads done; ldsCol[t&1] visible
        if (!diag && tid < BN) {
            float e = 0.f;
            #pragma unroll
            for (int w2 = 0; w2 < 8; w2++) e += ldsCol[t & 1][w2][tid];
            CE[r * NB + col0 + tid] = e;
        }
        // no second barrier: next iter writes ldsCol[(t+1)&1] (other parity)

        if (t + 1 < cnt && g + 1 == nA) {   // strip switch (at most once per block)
            flushRows();
            loadA(s);
        }
    }
    flushRows();

    // ---- centroid slice: rows (bid>>5)*1024.., dims (bid&31)*8 .. +7 ----
    __syncthreads();
    float* accW = (float*)ldsB;             // 8 waves x 128 classes x 8 dims = 32 KB
    for (int i = tid; i < 8192; i += 512) accW[i] = 0.f;
    __syncthreads();
    {
        const int rbase = (blockIdx.x >> 5) * 1024 + w * 128;
        const int d0 = (blockIdx.x & 31) * 8;
        #pragma unroll
        for (int k = 0; k < 2; k++) {
            const int row = rbase + k * 64 + l;
            const s8v v = *(const s8v*)(fb + row * DD + d0);
            const int c = lab[row];
            #pragma unroll
            for (int d = 0; d < 8; d++)
                atomicAdd(&accW[(w * 128 + c) * 8 + d], bf2f(v[d]));
        }
    }
    __syncthreads();
    {
        const int d0 = (blockIdx.x & 31) * 8;
        for (int i = tid; i < 1024; i += 512) {
            const int c = i >> 3, d = i & 7;
            float sum = 0.f;
            #pragma unroll
            for (int w2 = 0; w2 < 8; w2++) sum += accW[(w2 * 128 + c) * 8 + d];
            atomicAdd(&C[c * DD + d0 + d], sum);
        }
    }
}

// per-row finalize; 32 blocks of 256 (block = one 256-row strip).
// se = SEa[row] + sum_{r>strip} CE[r][row]
// spa = f_row . C[lab_row] - f_row . f_row   (positive-sim sum, self removed)
// loss_row = log(se*CEXP + 1e-8) - (spa - n)*INV_T/n
// Chunk fallback provably dead: CHUNK=256 > NUM_CLASSES=128.
__global__ void k_rows(const int* __restrict__ lab, const __hip_bfloat16* __restrict__ fb,
                       const float* __restrict__ SEa, const float* __restrict__ CE,
                       const float* __restrict__ C,
                       float* __restrict__ CL, float* __restrict__ CV,
                       int* __restrict__ cnt, float* __restrict__ out) {
    __shared__ int h[128];
    const int t = threadIdx.x;
    if (t < 128) h[t] = 0;
    __syncthreads();
    #pragma unroll
    for (int i = 0; i < 32; i++)
        atomicAdd(&h[lab[t + i * 256]], 1);
    __syncthreads();

    const int row = blockIdx.x * 256 + t;
    float se = SEa[row];
    for (int r = blockIdx.x + 1; r < NSTRIP; r++)
        se += CE[r * NB + row];

    // spa via centroid dot (f32)
    const s8v* fi8 = (const s8v*)(fb + row * DD);
    const float4* Cl4 = (const float4*)(C + lab[row] * DD);
    float spa = 0.f, selfdot = 0.f;
    #pragma unroll
    for (int q = 0; q < 32; q++) {
        const s8v v = fi8[q];
        const float4 ca = Cl4[2 * q], cb = Cl4[2 * q + 1];
        const float f0 = bf2f(v[0]), f1 = bf2f(v[1]), f2 = bf2f(v[2]), f3 = bf2f(v[3]);
        const float f4 = bf2f(v[4]), f5 = bf2f(v[5]), f6 = bf2f(v[6]), f7 = bf2f(v[7]);
        spa += f0 * ca.x + f1 * ca.y + f2 * ca.z + f3 * ca.w
             + f4 * cb.x + f5 * cb.y + f6 * cb.z + f7 * cb.w;
        selfdot += f0 * f0 + f1 * f1 + f2 * f2 + f3 * f3
                 + f4 * f4 + f5 * f5 + f6 * f6 + f7 * f7;
    }
    spa -= selfdot;   // exclude self

    const int n = h[lab[row]] - 1;
    const float lse = logf(se * CEXP + 1e-8f);
    const bool valid = n > 0;
    float loss = valid ? (lse - (spa - (float)n) * INV_T / (float)n) : 0.f;
    float vf = valid ? 1.f : 0.f;
    #pragma unroll
    for (int d = 32; d; d >>= 1) { loss += __shfl_xor(loss, d, 64); vf += __shfl_xor(vf, d, 64); }
    __shared__ float pl[4], pv[4];
    __shared__ int isLast;
    if ((t & 63) == 0) { pl[t >> 6] = loss; pv[t >> 6] = vf; }
    __syncthreads();
    if (t == 0) {
        CL[blockIdx.x] = pl[0] + pl[1] + pl[2] + pl[3];
        CV[blockIdx.x] = pv[0] + pv[1] + pv[2] + pv[3];
        __threadfence();                       // release CL/CV
        isLast = (atomicAdd(cnt, 1) == 31);
    }
    __syncthreads();
    if (isLast) {
        __threadfence();                       // acquire others' CL/CV
        float lsum = (t < 32) ? CL[t] : 0.f;
        float vsum = (t < 32) ? CV[t] : 0.f;
        #pragma unroll
        for (int d = 32; d; d >>= 1) { lsum += __shfl_xor(lsum, d, 64); vsum += __shfl_xor(vsum, d, 64); }
        if (t == 0) {
            const float mean = lsum / (vsum + 1e-8f);
            out[0] = mean;   // loss (reduction == 'mean')
            out[1] = vsum;   // total_pairs
            out[2] = mean;   // mean_loss
        }
    }
}

extern "C" void kernel_launch(void* const* d_in, const int* in_sizes, int n_in,
                              void* d_out, int out_size, void* d_ws, size_t ws_size,
                              hipStream_t stream) {
    (void)in_sizes; (void)n_in; (void)out_size; (void)ws_size;
    const float* feat = (const float*)d_in[0];
    const int*   lab  = (const int*)d_in[1];
    char* ws = (char*)d_ws;
    __hip_bfloat16* fb = (__hip_bfloat16*)(ws + OFF_FB);
    float* SEa = (float*)(ws + OFF_SEA);
    float* CE  = (float*)(ws + OFF_CE);
    float* C   = (float*)(ws + OFF_C);
    float* CL  = (float*)(ws + OFF_CL);
    float* CV  = (float*)(ws + OFF_CV);
    int*   cnt = (int*)(ws + OFF_CNT);
    float* out = (float*)d_out;

    hipLaunchKernelGGL(k_norm, dim3(NB / 4), dim3(256), 0, stream, feat, fb, SEa, C, cnt);
    hipLaunchKernelGGL(k_main, dim3(256), dim3(512), 0, stream, fb, lab, SEa, CE, C);
    hipLaunchKernelGGL(k_rows, dim3(NB / 256), dim3(256), 0, stream, lab, fb, SEa, CE, C, CL, CV, cnt, out);
}

// Round 14
// 90.472 us; speedup vs baseline: 1.1584x; 1.1584x over previous
//
#include <hip/hip_runtime.h>
#include <hip/hip_bf16.h>

#define NB 8192
#define DD 256
#define INV_T (1.0f/0.07f)
#define LOG2E 1.4426950408889634f
#define K1    (INV_T*LOG2E)          // logit (log2 units) = acc*K1 - K1
#define CEXP  6.2087204553847255e-7f // exp(-1/0.07): folds the -K1 term into se
#define NSTRIP 32
#define TILE 256
#define BN 64
#define BUFB (BN*DD*2)       // 32768 bytes per LDS buffer

typedef __attribute__((ext_vector_type(8))) short s8v;   // 8 bf16
typedef __attribute__((ext_vector_type(4))) float f4v;   // 4 f32 acc
typedef unsigned int u32;
typedef unsigned short u16;

// workspace layout (bytes)
#define OFF_FB   0                                  // bf16 normalized features: 4 MB
#define OFF_CE   (4*1024*1024)                      // f32[32][8192] col-sum slots (no zero)
#define OFF_SEA  (OFF_CE + NSTRIP*NB*4)             // f32[8192]  -- zeroed by memset
#define OFF_C    (OFF_SEA + NB*4)                   // f32[128][256] centroids -- zeroed
#define OFF_HIST (OFF_C + 128*DD*4)                 // int[128] -- zeroed
#define OFF_CNT  (OFF_HIST + 512)                   // int[1] -- zeroed
#define ZERO_BYTES (NB*4 + 128*DD*4 + 512 + 128)    // SEa+C+hist+cnt span
#define OFF_CL   (OFF_CNT + 128)                    // f32[256]
#define OFF_CV   (OFF_CL + 1024)                    // f32[256]

__device__ __forceinline__ float bf2f(short h) {
    u32 x = ((u32)(u16)h) << 16;
    return *(float*)&x;
}

// wave-per-row normalize + global label histogram (hist pre-zeroed by memset)
__global__ void k_norm(const float* __restrict__ feat, const int* __restrict__ lab,
                       __hip_bfloat16* __restrict__ fb, int* __restrict__ hist) {
    const int t = threadIdx.x;
    const int w = t >> 6, l = t & 63;
    const int row = blockIdx.x * 4 + w;
    const float4 v = ((const float4*)feat)[row * 64 + l];
    float s = v.x * v.x + v.y * v.y + v.z * v.z + v.w * v.w;
    #pragma unroll
    for (int d = 32; d; d >>= 1) s += __shfl_xor(s, d, 64);
    const float scale = 1.0f / fmaxf(sqrtf(s), 1e-12f);
    __hip_bfloat16 h0 = __float2bfloat16(v.x * scale);
    __hip_bfloat16 h1 = __float2bfloat16(v.y * scale);
    __hip_bfloat16 h2 = __float2bfloat16(v.z * scale);
    __hip_bfloat16 h3 = __float2bfloat16(v.w * scale);
    ushort4 o;
    o.x = *(u16*)&h0; o.y = *(u16*)&h1; o.z = *(u16*)&h2; o.w = *(u16*)&h3;
    ((ushort4*)fb)[row * 64 + l] = o;
    if (l == 0) atomicAdd(&hist[lab[row]], 1);
}

__device__ __forceinline__ void gld16(const void* g, void* l) {
    __builtin_amdgcn_global_load_lds((const __attribute__((address_space(1))) u32*)g,
                                     (__attribute__((address_space(3))) u32*)l, 16, 0, 0);
}

// Symmetric fused sim + exp row/col reduction — persistent balanced blocks (R13).
// Positive sums handled analytically via class centroids. Epilogue is exp-only.
__launch_bounds__(512)
__global__ void k_main(const __hip_bfloat16* __restrict__ fb,
                       const int* __restrict__ lab,
                       float* __restrict__ SEa, float* __restrict__ CE,
                       float* __restrict__ C) {
    __shared__ __align__(16) char ldsB[2 * BUFB];   // 64 KB, XOR-swizzled
    __shared__ float ldsCol[2][8][BN];              // 4 KB parity-buffered col partials
    const int tid = threadIdx.x;
    const int w = tid >> 6;
    const int l = tid & 63;
    const int l15 = l & 15, lg = l >> 4;

    const int s = blockIdx.x >> 4;          // pair 0..15
    const int j = blockIdx.x & 15;          // block within pair
    const int nA = 4 * (32 - s);            // iters of strip A = 31-s
    const int cnt = 8 + (j >= 12 ? 1 : 0);  // 12x8 + 4x9 = 132
    const int off = 8 * j + (j > 12 ? j - 12 : 0);

    s8v a[2][8];
    int wbase = 0;
    auto loadA = [&](int r) {
        wbase = r * TILE + w * 32;
        #pragma unroll
        for (int m = 0; m < 2; m++)
            #pragma unroll
            for (int kk = 0; kk < 8; kk++)
                a[m][kk] = *(const s8v*)(fb + (wbase + m * 16 + l15) * DD + kk * 32 + lg * 8);
    };

    float sE[8];
    #pragma unroll
    for (int i = 0; i < 8; i++) sE[i] = 0.f;
    auto flushRows = [&]() {
        #pragma unroll
        for (int idx = 0; idx < 8; idx++)
            #pragma unroll
            for (int d = 1; d < 16; d <<= 1)
                sE[idx] += __shfl_xor(sE[idx], d, 16);
        if (l15 == 0) {
            #pragma unroll
            for (int idx = 0; idx < 8; idx++) {
                const int row = wbase + (idx >> 2) * 16 + lg * 4 + (idx & 3);
                atomicAdd(&SEa[row], sE[idx]);
            }
        }
        #pragma unroll
        for (int i = 0; i < 8; i++) sE[i] = 0.f;
    };

    auto stage = [&](int g, int bufoff) {
        const int c0 = (g < nA ? g : g - nA) * 64;
        const char* gt = (const char*)fb + (size_t)c0 * (DD * 2);
        #pragma unroll
        for (int i = 0; i < 4; i++) {
            const int x = i * 8192 + (tid << 4);
            const int br = x >> 9;
            const int inrow = x & 511;
            gld16(gt + br * 512 + (inrow ^ ((br & 7) << 4)),
                  ldsB + bufoff + i * 8192 + w * 1024);
        }
    };

    stage(off, 0);
    loadA(off < nA ? 31 - s : s);
    __syncthreads();

    for (int t = 0; t < cnt; t++) {
        const int g = off + t;
        const int curoff = (t & 1) * BUFB;
        if (t + 1 < cnt) stage(g + 1, curoff ^ BUFB);

        const int r = (g < nA) ? 31 - s : s;
        const int i = (g < nA) ? g : g - nA;
        const int col0 = i * 64;
        const bool diag = ((i >> 2) == r);

        f4v acc[2][4];
        #pragma unroll
        for (int m = 0; m < 2; m++)
            #pragma unroll
            for (int n = 0; n < 4; n++)
                acc[m][n] = (f4v){0.f, 0.f, 0.f, 0.f};

        #pragma unroll
        for (int kk = 0; kk < 8; kk++) {
            s8v bfr[4];
            #pragma unroll
            for (int n = 0; n < 4; n++) {
                const int br = n * 16 + l15;
                const int ad = (br * 512 + kk * 64 + lg * 16) ^ ((br & 7) << 4);
                bfr[n] = *(const s8v*)(ldsB + curoff + ad);
            }
            #pragma unroll
            for (int m = 0; m < 2; m++)
                #pragma unroll
                for (int n = 0; n < 4; n++)
                    acc[m][n] = __builtin_amdgcn_mfma_f32_16x16x32_bf16(a[m][kk], bfr[n], acc[m][n], 0, 0, 0);
        }

        float cE[4];
        #pragma unroll
        for (int n = 0; n < 4; n++) {
            float cEn = 0.f;
            #pragma unroll
            for (int m = 0; m < 2; m++)
                #pragma unroll
                for (int rr = 0; rr < 4; rr++) {
                    const int idx = m * 4 + rr;
                    float e = exp2f(acc[m][n][rr] * K1);  // true e = CEXP * this
                    if (diag) {
                        const int row = wbase + m * 16 + lg * 4 + rr;
                        const int coln = col0 + n * 16 + l15;
                        e = (row != coln) ? e : 0.f;
                    }
                    sE[idx] += e;
                    cEn += e;
                }
            cE[n] = cEn;
        }

        if (!diag) {
            #pragma unroll
            for (int n = 0; n < 4; n++) {
                cE[n] += __shfl_xor(cE[n], 16, 64);
                cE[n] += __shfl_xor(cE[n], 32, 64);
            }
            if (l < 16) {
                #pragma unroll
                for (int n = 0; n < 4; n++)
                    ldsCol[t & 1][w][n * 16 + l15] = cE[n];
            }
        }
        __syncthreads();
        if (!diag && tid < BN) {
            float e = 0.f;
            #pragma unroll
            for (int w2 = 0; w2 < 8; w2++) e += ldsCol[t & 1][w2][tid];
            CE[r * NB + col0 + tid] = e;
        }

        if (t + 1 < cnt && g + 1 == nA) {
            flushRows();
            loadA(s);
        }
    }
    flushRows();

    // ---- centroid slice: rows (bid>>5)*1024.., dims (bid&31)*8 .. +7 ----
    __syncthreads();
    float* accW = (float*)ldsB;             // 8 waves x 128 classes x 8 dims = 32 KB
    for (int i = tid; i < 8192; i += 512) accW[i] = 0.f;
    __syncthreads();
    {
        const int rbase = (blockIdx.x >> 5) * 1024 + w * 128;
        const int d0 = (blockIdx.x & 31) * 8;
        #pragma unroll
        for (int k = 0; k < 2; k++) {
            const int row = rbase + k * 64 + l;
            const s8v v = *(const s8v*)(fb + row * DD + d0);
            const int c = lab[row];
            #pragma unroll
            for (int d = 0; d < 8; d++)
                atomicAdd(&accW[(w * 128 + c) * 8 + d], bf2f(v[d]));
        }
    }
    __syncthreads();
    {
        const int d0 = (blockIdx.x & 31) * 8;
        for (int i = tid; i < 1024; i += 512) {
            const int c = i >> 3, d = i & 7;
            float sum = 0.f;
            #pragma unroll
            for (int w2 = 0; w2 < 8; w2++) sum += accW[(w2 * 128 + c) * 8 + d];
            atomicAdd(&C[c * DD + d0 + d], sum);
        }
    }
}

// Parallel finalize: 256 blocks x 32 rows. All loads staged coalesced into LDS.
// se = SEa[row] + sum_{r>strip} CE[r][row]
// spa = f_row . C[lab_row] - f_row . f_row ;  loss = lse - (spa - n)*INV_T/n
// Chunk fallback provably dead: CHUNK=256 > NUM_CLASSES=128.
__global__ void k_rows(const int* __restrict__ lab, const __hip_bfloat16* __restrict__ fb,
                       const float* __restrict__ SEa, const float* __restrict__ CE,
                       const float* __restrict__ C, const int* __restrict__ hist,
                       float* __restrict__ CL, float* __restrict__ CV,
                       int* __restrict__ cnt, float* __restrict__ out) {
    __shared__ float fLds[32][DD];     // 32 KB  f32 feature rows
    __shared__ float cLds[32][DD];     // 32 KB  centroid rows for each row's class
    __shared__ float ceLds[8][32];     // CE partials
    __shared__ float rowSpa[32], rowSelf[32];
    __shared__ float pl4[4], pv4[4];
    __shared__ int isLast;
    const int t = threadIdx.x;
    const int b = blockIdx.x;
    const int row0 = b * 32;
    const int c0 = row0 >> 8;          // 256-row strip index

    // stage f rows (s8v -> f32), coalesced
    #pragma unroll
    for (int i = 0; i < 4; i++) {
        const int idx = t + i * 256;   // s8v index within [32][32]
        const s8v v = ((const s8v*)(fb + row0 * DD))[idx];
        #pragma unroll
        for (int d = 0; d < 8; d++)
            (&fLds[0][0])[idx * 8 + d] = bf2f(v[d]);
    }
    // stage centroid rows (float4), coalesced; 4 rows per iteration
    #pragma unroll
    for (int i = 0; i < 8; i++) {
        const int idx = t + i * 256;   // float4 index within [32][64]
        const int r = idx >> 6, dq = idx & 63;
        const int c = lab[row0 + r];
        ((float4*)&cLds[0][0])[idx] = ((const float4*)(C + c * DD))[dq];
    }
    // CE strip partials, coalesced (32 consecutive rows per 32-lane group)
    {
        const int rg = t >> 5, rl = t & 31;
        float s = 0.f;
        for (int r = c0 + 1 + rg; r < NSTRIP; r += 8)
            s += CE[r * NB + row0 + rl];
        ceLds[rg][rl] = s;
    }
    __syncthreads();

    // dots: 8 threads per row, 32 dims each, width-8 shuffle reduce
    {
        const int rl = t >> 3, j = t & 7;
        float sp = 0.f, sf = 0.f;
        #pragma unroll
        for (int q = 0; q < 32; q++) {
            const float fv = fLds[rl][j * 32 + q];
            sp += fv * cLds[rl][j * 32 + q];
            sf += fv * fv;
        }
        #pragma unroll
        for (int d = 1; d < 8; d <<= 1) {
            sp += __shfl_xor(sp, d, 8);
            sf += __shfl_xor(sf, d, 8);
        }
        if (j == 0) { rowSpa[rl] = sp; rowSelf[rl] = sf; }
    }
    __syncthreads();

    float bl = 0.f, bv = 0.f;
    if (t < 32) {
        const int row = row0 + t;
        float ce = 0.f;
        #pragma unroll
        for (int g = 0; g < 8; g++) ce += ceLds[g][t];
        const float se = SEa[row] + ce;
        const float spa = rowSpa[t] - rowSelf[t];
        const int n = hist[lab[row]] - 1;
        const float lse = logf(se * CEXP + 1e-8f);
        const bool valid = n > 0;
        bl = valid ? (lse - (spa - (float)n) * INV_T / (float)n) : 0.f;
        bv = valid ? 1.f : 0.f;
    }
    if (t < 64) {
        #pragma unroll
        for (int d = 1; d < 32; d <<= 1) {
            bl += __shfl_xor(bl, d, 32);
            bv += __shfl_xor(bv, d, 32);
        }
    }
    if (t == 0) {
        CL[b] = bl;
        CV[b] = bv;
        __threadfence();                       // release CL/CV
        isLast = (atomicAdd(cnt, 1) == 255);
    }
    __syncthreads();
    if (isLast) {
        __threadfence();                       // acquire others' CL/CV
        float lsum = CL[t], vsum = CV[t];      // 256 blocks, 1:1 with threads
        #pragma unroll
        for (int d = 32; d; d >>= 1) { lsum += __shfl_xor(lsum, d, 64); vsum += __shfl_xor(vsum, d, 64); }
        if ((t & 63) == 0) { pl4[t >> 6] = lsum; pv4[t >> 6] = vsum; }
        __syncthreads();
        if (t == 0) {
            const float L = pl4[0] + pl4[1] + pl4[2] + pl4[3];
            const float V = pv4[0] + pv4[1] + pv4[2] + pv4[3];
            const float mean = L / (V + 1e-8f);
            out[0] = mean;   // loss (reduction == 'mean')
            out[1] = V;      // total_pairs
            out[2] = mean;   // mean_loss
        }
    }
}

extern "C" void kernel_launch(void* const* d_in, const int* in_sizes, int n_in,
                              void* d_out, int out_size, void* d_ws, size_t ws_size,
                              hipStream_t stream) {
    (void)in_sizes; (void)n_in; (void)out_size; (void)ws_size;
    const float* feat = (const float*)d_in[0];
    const int*   lab  = (const int*)d_in[1];
    char* ws = (char*)d_ws;
    __hip_bfloat16* fb = (__hip_bfloat16*)(ws + OFF_FB);
    float* CE   = (float*)(ws + OFF_CE);
    float* SEa  = (float*)(ws + OFF_SEA);
    float* C    = (float*)(ws + OFF_C);
    int*   hist = (int*)(ws + OFF_HIST);
    int*   cnt  = (int*)(ws + OFF_CNT);
    float* CL   = (float*)(ws + OFF_CL);
    float* CV   = (float*)(ws + OFF_CV);
    float* out  = (float*)d_out;

    hipMemsetAsync(ws + OFF_SEA, 0, ZERO_BYTES, stream);   // SEa, C, hist, cnt
    hipLaunchKernelGGL(k_norm, dim3(NB / 4), dim3(256), 0, stream, feat, lab, fb, hist);
    hipLaunchKernelGGL(k_main, dim3(256), dim3(512), 0, stream, fb, lab, SEa, CE, C);
    hipLaunchKernelGGL(k_rows, dim3(256), dim3(256), 0, stream, lab, fb, SEa, CE, C, hist, CL, CV, cnt, out);
}